// Round 13
// baseline (85.306 us; speedup 1.0000x reference)
//
#include <hip/hip_runtime.h>
#include <math.h>

#define N 4096
#define D 512
#define KPOS 5
#define KNEG 10
#define NB 32                      // 4096/128 block-rows
#define NPAIR (NB * (NB - 1) / 2)  // 496 strict upper pairs
#define NJOB 1024                  // 992 off-diag half-jobs + 32 diag half-jobs

typedef short s16x8 __attribute__((ext_vector_type(8)));
typedef unsigned short u16x8 __attribute__((ext_vector_type(8)));
typedef float f32x4 __attribute__((ext_vector_type(4)));

__device__ __forceinline__ unsigned short f2bf(float x) {
    unsigned u = __float_as_uint(x);
    unsigned r = (u + 0x7FFFu + ((u >> 16) & 1u)) >> 16;   // RNE
    return (unsigned short)r;
}
__device__ __forceinline__ float bf2f(unsigned short b) {
    return __uint_as_float(((unsigned)b) << 16);
}
// bf16 -> sortable u16 (ascending u16 order == ascending float order)
__device__ __forceinline__ unsigned short mapbf(float x) {
    const unsigned short h = f2bf(x);
    return h ^ ((h & 0x8000u) ? 0xFFFFu : 0x8000u);
}
__device__ __forceinline__ unsigned umax_(unsigned a, unsigned b) { return a > b ? a : b; }
__device__ __forceinline__ unsigned umin_(unsigned a, unsigned b) { return a < b ? a : b; }

// ---------------------------------------------------------------------------
// Kernel 1: normalize. anchor rows (eps 1e-8) -> bf16 A; sample rows
// (eps 1e-12) -> bf16 s_norm. Block 0 re-zeroes the fused kernel's counter.
// ---------------------------------------------------------------------------
__global__ __launch_bounds__(256) void norm_kernel(const float* __restrict__ anchor,
                                                   const float* __restrict__ sample,
                                                   unsigned short* __restrict__ Abf,
                                                   unsigned short* __restrict__ s_norm,
                                                   unsigned* __restrict__ counter) {
    if (blockIdx.x == 0 && threadIdx.x == 0) *counter = 0u;
    const int wave = threadIdx.x >> 6, lane = threadIdx.x & 63;
    const int row = blockIdx.x * 4 + wave;
    const bool is_anchor = row < N;
    const float* in = is_anchor ? anchor + (size_t)row * D
                                : sample + (size_t)(row - N) * D;
    const float eps = is_anchor ? 1e-8f : 1e-12f;

    float v[8];
    float ss = 0.f;
#pragma unroll
    for (int e = 0; e < 8; ++e) {
        v[e] = in[lane + 64 * e];
        ss = fmaf(v[e], v[e], ss);
    }
#pragma unroll
    for (int off = 32; off > 0; off >>= 1) ss += __shfl_xor(ss, off);
    const float denom = fmaxf(sqrtf(ss), eps);

    unsigned short* out = is_anchor ? Abf + (size_t)row * D
                                    : s_norm + (size_t)(row - N) * D;
#pragma unroll
    for (int e = 0; e < 8; ++e) out[lane + 64 * e] = f2bf(v[e] / denom);
}

// ---------------------------------------------------------------------------
// Kernel 2: sim = A@A^T, bf16 MFMA, K = 512. 1024 balanced half-jobs
// (128 rows x 64 cols). Output = SORTABLE-MAPPED u16 (the topk scan's
// monotone map is applied here, in the idle epilogue). Off-diag jobs write
// normal + transposed mirror. T1 XCD chunk swizzle, T2 LDS XOR swizzle via
// pre-swizzled global source, dbuf prefetch-before-compute.
// ---------------------------------------------------------------------------
#define ATILE (128 * 64)
#define BTILE (64 * 64)

__device__ __forceinline__ void stage_ab(const unsigned short* __restrict__ A,
                                         unsigned short* As, unsigned short* Bs,
                                         int rowA, int colB, int kl, int t) {
#pragma unroll
    for (int i = 0; i < 4; ++i) {
        const int c = i * 256 + t;                 // 16B chunk id 0..1023
        const int r = c >> 3;                      // tile row 0..127
        const int ke = ((c & 7) ^ (r & 7)) * 8;    // swizzled k-element offset
        __builtin_amdgcn_global_load_lds(
            (const __attribute__((address_space(1))) void*)(A + (size_t)(rowA + r) * D + kl + ke),
            (__attribute__((address_space(3))) void*)(As + c * 8), 16, 0, 0);
    }
#pragma unroll
    for (int i = 0; i < 2; ++i) {
        const int c = i * 256 + t;                 // 0..511
        const int r = c >> 3;                      // B tile row 0..63
        const int ke = ((c & 7) ^ (r & 7)) * 8;
        __builtin_amdgcn_global_load_lds(
            (const __attribute__((address_space(1))) void*)(A + (size_t)(colB + r) * D + kl + ke),
            (__attribute__((address_space(3))) void*)(Bs + c * 8), 16, 0, 0);
    }
}

__global__ __launch_bounds__(256) void gemm_bf16(const unsigned short* __restrict__ Abf,
                                                 unsigned short* __restrict__ C) {
    // T1: XCD chunk swizzle (bijective, NJOB % 8 == 0).
    const int q = (blockIdx.x % 8) * (NJOB / 8) + blockIdx.x / 8;

    int bi, bj, h;
    if (q < 2 * NPAIR) {
        const int op = q >> 1;                 // strict pair index 0..495
        h = q & 1;
        bi = (int)(31.5f - sqrtf(31.5f * 31.5f - 2.f * (float)op));
        while (31 * bi - bi * (bi - 1) / 2 > op) --bi;
        while (31 * (bi + 1) - (bi + 1) * bi / 2 <= op) ++bi;
        bj = bi + 1 + (op - (31 * bi - bi * (bi - 1) / 2));
    } else {
        const int d = q - 2 * NPAIR;           // 0..31
        bi = bj = d >> 1;
        h = d & 1;
    }

    __shared__ __align__(16) unsigned short As[2 * ATILE];   // 2 x 16 KiB
    __shared__ __align__(16) unsigned short Bs[2 * BTILE];   // 2 x 8 KiB

    const int t = threadIdx.x;
    const int l = t & 63;
    const int w = t >> 6;
    const int wr = w >> 1, wc = w & 1;         // wave tile: 64 rows x 32 cols
    const int rowA = bi * 128;
    const int colB = bj * 128 + h * 64;
    const int lrow = l & 15, lgrp = l >> 4;

    f32x4 acc[4][2];
#pragma unroll
    for (int m = 0; m < 4; ++m)
#pragma unroll
        for (int n = 0; n < 2; ++n) acc[m][n] = (f32x4){0.f, 0.f, 0.f, 0.f};

    stage_ab(Abf, As, Bs, rowA, colB, 0, t);
    __syncthreads();

    for (int kc = 0; kc < 8; ++kc) {
        const int cur = kc & 1;
        if (kc < 7)
            stage_ab(Abf, As + (cur ^ 1) * ATILE, Bs + (cur ^ 1) * BTILE,
                     rowA, colB, (kc + 1) * 64, t);

        const char* AsB = (const char*)(As + cur * ATILE);
        const char* BsB = (const char*)(Bs + cur * BTILE);
#pragma unroll
        for (int kk = 0; kk < 2; ++kk) {
            s16x8 af[4], bfr[2];
#pragma unroll
            for (int m = 0; m < 4; ++m) {
                const int row = wr * 64 + m * 16 + lrow;
                af[m] = *(const s16x8*)(AsB + row * 128 + (((kk * 4 + lgrp) ^ (row & 7)) * 16));
            }
#pragma unroll
            for (int n = 0; n < 2; ++n) {
                const int row = wc * 32 + n * 16 + lrow;   // B tile row 0..63
                bfr[n] = *(const s16x8*)(BsB + row * 128 + (((kk * 4 + lgrp) ^ (row & 7)) * 16));
            }
#pragma unroll
            for (int m = 0; m < 4; ++m)
#pragma unroll
                for (int n = 0; n < 2; ++n)
                    acc[m][n] = __builtin_amdgcn_mfma_f32_16x16x32_bf16(af[m], bfr[n], acc[m][n], 0, 0, 0);
        }
        __syncthreads();
    }

    // C/D layout: col = lane&15, row = (lane>>4)*4 + j ; store MAPPED u16.
#pragma unroll
    for (int m = 0; m < 4; ++m) {
#pragma unroll
        for (int n = 0; n < 2; ++n) {
            const int col = colB + wc * 32 + n * 16 + lrow;
            const int row0 = rowA + wr * 64 + m * 16 + lgrp * 4;
#pragma unroll
            for (int j = 0; j < 4; ++j)
                C[(size_t)(row0 + j) * N + col] = mapbf(acc[m][n][j]);
        }
    }
    if (bi != bj) {
        // mirror: C[col][row0..row0+3] — 4 consecutive u16 = 8B store.
#pragma unroll
        for (int m = 0; m < 4; ++m) {
#pragma unroll
            for (int n = 0; n < 2; ++n) {
                const int col = colB + wc * 32 + n * 16 + lrow;
                const int row0 = rowA + wr * 64 + m * 16 + lgrp * 4;
                ushort4 pk;
                pk.x = mapbf(acc[m][n][0]);
                pk.y = mapbf(acc[m][n][1]);
                pk.z = mapbf(acc[m][n][2]);
                pk.w = mapbf(acc[m][n][3]);
                *(ushort4*)&C[(size_t)col * N + row0] = pk;
            }
        }
    }
}

// ---------------------------------------------------------------------------
// Kernel 3: FUSED topk + loss + final reduce. One wave per anchor row ia.
// Phase A: branchless top-5/bot-10 over pre-mapped u16 sim (key = u16<<16 |
// idx; idx complemented for top -> jax stable tie order); winner indices
// captured into rowB via predicated select.
// Phase B: MFMA loss (A rows = 5 queries, B cols = 5 pos + 10 neg), 32
// up-front 16B gathers, 16 chained MFMAs, 16-lane-group softmax.
// Phase C: block partial -> partials[]; last block (device-scope counter)
// reduces all 1024 partials in fixed order and writes *out. Deterministic.
// ---------------------------------------------------------------------------
__global__ __launch_bounds__(256) void fused_topk_loss(const unsigned short* __restrict__ sim,
                                                       const unsigned short* __restrict__ s_norm,
                                                       float* __restrict__ partials,
                                                       unsigned* __restrict__ counter,
                                                       float* __restrict__ out) {
    __shared__ float wsum[4];
    __shared__ int lastflag;
    const int wave = threadIdx.x >> 6, lane = threadIdx.x & 63;
    const int ia = blockIdx.x * 4 + wave;
    const unsigned short* s = sim + (size_t)ia * N;
    const int cc = lane & 15;               // loss column selector
    const int g = lane >> 4;                // loss k-group

    unsigned tk[KPOS], bk[KNEG];
#pragma unroll
    for (int qq = 0; qq < KPOS; ++qq) tk[qq] = 0u;
#pragma unroll
    for (int qq = 0; qq < KNEG; ++qq) bk[qq] = 0xFFFFFFFFu;

    for (int e = 0; e < 8; ++e) {
        const int base = 8 * (lane + 64 * e);
        const u16x8 v8 = *(const u16x8*)&s[base];
#pragma unroll
        for (int j = 0; j < 8; ++j) {
            const unsigned kv = ((unsigned)v8[j]) << 16;     // pre-mapped
            const int idx = base + j;

            unsigned c = kv | (unsigned)(4095 - idx);        // top key
#pragma unroll
            for (int qq = 0; qq < KPOS - 1; ++qq) {
                const unsigned x = umax_(tk[qq], c);
                c = umin_(tk[qq], c);
                tk[qq] = x;
            }
            tk[KPOS - 1] = umax_(tk[KPOS - 1], c);

            c = kv | (unsigned)idx;                          // bot key
#pragma unroll
            for (int qq = 0; qq < KNEG - 1; ++qq) {
                const unsigned x = umin_(bk[qq], c);
                c = umax_(bk[qq], c);
                bk[qq] = x;
            }
            bk[KNEG - 1] = umax_(bk[KNEG - 1], c);
        }
    }

    int rowB = 0;                            // (cc==15 dummy stays 0)
#pragma unroll
    for (int it = 0; it < KPOS; ++it) {
        unsigned m = tk[0];
#pragma unroll
        for (int off = 32; off > 0; off >>= 1) m = umax_(m, (unsigned)__shfl_xor((int)m, off));
        const int widx = 4095 - (int)(m & 0xFFFu);
        if (cc == it) rowB = widx;
        if (tk[0] == m) {
#pragma unroll
            for (int qq = 0; qq < KPOS - 1; ++qq) tk[qq] = tk[qq + 1];
            tk[KPOS - 1] = 0u;
        }
    }
#pragma unroll
    for (int it = 0; it < KNEG; ++it) {
        unsigned m = bk[0];
#pragma unroll
        for (int off = 32; off > 0; off >>= 1) m = umin_(m, (unsigned)__shfl_xor((int)m, off));
        const int widx = (int)(m & 0xFFFu);
        if (cc == KPOS + it) rowB = widx;
        if (bk[0] == m) {
#pragma unroll
            for (int qq = 0; qq < KNEG - 1; ++qq) bk[qq] = bk[qq + 1];
            bk[KNEG - 1] = 0xFFFFFFFFu;
        }
    }

    // ---- loss: A rows = query rows (ia*5+p mod N), B cols = pos/neg ----
    const int rowA = (ia * KPOS + ((cc < KPOS) ? cc : 0)) & (N - 1);
    const unsigned short* pA = s_norm + (size_t)rowA * D + g * 8;
    const unsigned short* pB = s_norm + (size_t)rowB * D + g * 8;

    s16x8 a[16], b[16];
#pragma unroll
    for (int kk = 0; kk < 16; ++kk) {
        a[kk] = *(const s16x8*)(pA + kk * 32);
        b[kk] = *(const s16x8*)(pB + kk * 32);
    }
    f32x4 acc = (f32x4){0.f, 0.f, 0.f, 0.f};
#pragma unroll
    for (int kk = 0; kk < 16; ++kk)
        acc = __builtin_amdgcn_mfma_f32_16x16x32_bf16(a[kk], b[kk], acc, 0, 0, 0);

    float lsum = 0.f;
#pragma unroll
    for (int j = 0; j < 4; ++j) {
        const int p = g * 4 + j;                 // output row (query p)
        const float logit = acc[j] * 10.f;
        const bool isneg = (cc >= KPOS) && (cc < 15);
        const bool ispos = (cc == p);
        float x = (ispos || isneg) ? logit : -__builtin_inff();
        float m = x;
#pragma unroll
        for (int off = 1; off < 16; off <<= 1) m = fmaxf(m, __shfl_xor(m, off));
        float e = (ispos || isneg) ? expf(logit - m) : 0.f;
        float sx = e;
#pragma unroll
        for (int off = 1; off < 16; off <<= 1) sx += __shfl_xor(sx, off);
        float l0 = ispos ? logit : 0.f;
#pragma unroll
        for (int off = 1; off < 16; off <<= 1) l0 += __shfl_xor(l0, off);
        if (p < KPOS && ispos) lsum += logf(sx) + m - l0;   // one lane per row
    }

#pragma unroll
    for (int off = 32; off > 0; off >>= 1) lsum += __shfl_xor(lsum, off);
    if (lane == 0) wsum[wave] = lsum;
    __syncthreads();
    if (threadIdx.x == 0) {
        partials[blockIdx.x] = wsum[0] + wsum[1] + wsum[2] + wsum[3];
        __threadfence();
        const unsigned tkt = atomicAdd(counter, 1u);
        lastflag = (tkt == (unsigned)(gridDim.x - 1));
    }
    __syncthreads();

    if (lastflag) {
        // device-scope re-read of all partials (atomicAdd 0 bypasses L1)
        float sacc = 0.f;
#pragma unroll
        for (int i = 0; i < 4; ++i)
            sacc += atomicAdd(&partials[threadIdx.x + 256 * i], 0.f);
#pragma unroll
        for (int off = 32; off > 0; off >>= 1) sacc += __shfl_xor(sacc, off);
        if (lane == 0) wsum[wave] = sacc;
        __syncthreads();
        if (threadIdx.x == 0)
            *out = (wsum[0] + wsum[1] + wsum[2] + wsum[3]) * (1.0f / (float)(N * KPOS));
    }
}

// ---------------------------------------------------------------------------
extern "C" void kernel_launch(void* const* d_in, const int* in_sizes, int n_in,
                              void* d_out, int out_size, void* d_ws, size_t ws_size,
                              hipStream_t stream) {
    const float* anchor = (const float*)d_in[0];
    const float* sample = (const float*)d_in[1];
    float* out = (float*)d_out;

    char* ws = (char*)d_ws;
    unsigned short* Abf    = (unsigned short*)ws;                               // 4 MiB
    unsigned short* s_norm = (unsigned short*)(ws + (size_t)4 * 1024 * 1024);   // 4 MiB
    unsigned short* sim    = (unsigned short*)(ws + (size_t)8 * 1024 * 1024);   // 32 MiB
    float* partials = (float*)(ws + (size_t)40 * 1024 * 1024);                  // 4 KiB
    unsigned* counter = (unsigned*)(ws + (size_t)40 * 1024 * 1024 + 4096);

    norm_kernel<<<2048, 256, 0, stream>>>(anchor, sample, Abf, s_norm, counter);

    gemm_bf16<<<NJOB, 256, 0, stream>>>(Abf, sim);

    fused_topk_loss<<<N / 4, 256, 0, stream>>>(sim, s_norm, partials, counter, out);
}

// Round 14
// 71.015 us; speedup vs baseline: 1.2012x; 1.2012x over previous
//
#include <hip/hip_runtime.h>
#include <math.h>

#define N 4096
#define D 512
#define KPOS 5
#define KNEG 10
#define NB 32                      // 4096/128 block-rows
#define NPAIR (NB * (NB - 1) / 2)  // 496 strict upper pairs
#define NJOB 1024                  // 992 off-diag half-jobs + 32 diag half-jobs

typedef short s16x8 __attribute__((ext_vector_type(8)));
typedef unsigned short u16x8 __attribute__((ext_vector_type(8)));
typedef float f32x4 __attribute__((ext_vector_type(4)));

__device__ __forceinline__ unsigned short f2bf(float x) {
    unsigned u = __float_as_uint(x);
    unsigned r = (u + 0x7FFFu + ((u >> 16) & 1u)) >> 16;   // RNE
    return (unsigned short)r;
}
__device__ __forceinline__ float bf2f(unsigned short b) {
    return __uint_as_float(((unsigned)b) << 16);
}
// bf16 -> sortable u16 (ascending u16 order == ascending float order)
__device__ __forceinline__ unsigned short mapbf(float x) {
    const unsigned short h = f2bf(x);
    return h ^ ((h & 0x8000u) ? 0xFFFFu : 0x8000u);
}
__device__ __forceinline__ unsigned umax_(unsigned a, unsigned b) { return a > b ? a : b; }
__device__ __forceinline__ unsigned umin_(unsigned a, unsigned b) { return a < b ? a : b; }

// ---------------------------------------------------------------------------
// Kernel 1: normalize. anchor rows (eps 1e-8) -> bf16 A; sample rows
// (eps 1e-12) -> bf16 s_norm.
// ---------------------------------------------------------------------------
__global__ __launch_bounds__(256) void norm_kernel(const float* __restrict__ anchor,
                                                   const float* __restrict__ sample,
                                                   unsigned short* __restrict__ Abf,
                                                   unsigned short* __restrict__ s_norm) {
    const int wave = threadIdx.x >> 6, lane = threadIdx.x & 63;
    const int row = blockIdx.x * 4 + wave;
    const bool is_anchor = row < N;
    const float* in = is_anchor ? anchor + (size_t)row * D
                                : sample + (size_t)(row - N) * D;
    const float eps = is_anchor ? 1e-8f : 1e-12f;

    float v[8];
    float ss = 0.f;
#pragma unroll
    for (int e = 0; e < 8; ++e) {
        v[e] = in[lane + 64 * e];
        ss = fmaf(v[e], v[e], ss);
    }
#pragma unroll
    for (int off = 32; off > 0; off >>= 1) ss += __shfl_xor(ss, off);
    const float denom = fmaxf(sqrtf(ss), eps);

    unsigned short* out = is_anchor ? Abf + (size_t)row * D
                                    : s_norm + (size_t)(row - N) * D;
#pragma unroll
    for (int e = 0; e < 8; ++e) out[lane + 64 * e] = f2bf(v[e] / denom);
}

// ---------------------------------------------------------------------------
// Kernel 2: sim = A@A^T, bf16 MFMA, K = 512. 1024 balanced half-jobs
// (128 rows x 64 cols). Output = SORTABLE-MAPPED u16. Off-diag jobs write
// normal + transposed mirror. T1 XCD chunk swizzle, T2 LDS XOR swizzle via
// pre-swizzled global source, dbuf prefetch-before-compute.
// ---------------------------------------------------------------------------
#define ATILE (128 * 64)
#define BTILE (64 * 64)

__device__ __forceinline__ void stage_ab(const unsigned short* __restrict__ A,
                                         unsigned short* As, unsigned short* Bs,
                                         int rowA, int colB, int kl, int t) {
#pragma unroll
    for (int i = 0; i < 4; ++i) {
        const int c = i * 256 + t;                 // 16B chunk id 0..1023
        const int r = c >> 3;                      // tile row 0..127
        const int ke = ((c & 7) ^ (r & 7)) * 8;    // swizzled k-element offset
        __builtin_amdgcn_global_load_lds(
            (const __attribute__((address_space(1))) void*)(A + (size_t)(rowA + r) * D + kl + ke),
            (__attribute__((address_space(3))) void*)(As + c * 8), 16, 0, 0);
    }
#pragma unroll
    for (int i = 0; i < 2; ++i) {
        const int c = i * 256 + t;                 // 0..511
        const int r = c >> 3;                      // B tile row 0..63
        const int ke = ((c & 7) ^ (r & 7)) * 8;
        __builtin_amdgcn_global_load_lds(
            (const __attribute__((address_space(1))) void*)(A + (size_t)(colB + r) * D + kl + ke),
            (__attribute__((address_space(3))) void*)(Bs + c * 8), 16, 0, 0);
    }
}

__global__ __launch_bounds__(256) void gemm_bf16(const unsigned short* __restrict__ Abf,
                                                 unsigned short* __restrict__ C) {
    // T1: XCD chunk swizzle (bijective, NJOB % 8 == 0).
    const int q = (blockIdx.x % 8) * (NJOB / 8) + blockIdx.x / 8;

    int bi, bj, h;
    if (q < 2 * NPAIR) {
        const int op = q >> 1;                 // strict pair index 0..495
        h = q & 1;
        bi = (int)(31.5f - sqrtf(31.5f * 31.5f - 2.f * (float)op));
        while (31 * bi - bi * (bi - 1) / 2 > op) --bi;
        while (31 * (bi + 1) - (bi + 1) * bi / 2 <= op) ++bi;
        bj = bi + 1 + (op - (31 * bi - bi * (bi - 1) / 2));
    } else {
        const int d = q - 2 * NPAIR;           // 0..31
        bi = bj = d >> 1;
        h = d & 1;
    }

    __shared__ __align__(16) unsigned short As[2 * ATILE];   // 2 x 16 KiB
    __shared__ __align__(16) unsigned short Bs[2 * BTILE];   // 2 x 8 KiB

    const int t = threadIdx.x;
    const int l = t & 63;
    const int w = t >> 6;
    const int wr = w >> 1, wc = w & 1;         // wave tile: 64 rows x 32 cols
    const int rowA = bi * 128;
    const int colB = bj * 128 + h * 64;
    const int lrow = l & 15, lgrp = l >> 4;

    f32x4 acc[4][2];
#pragma unroll
    for (int m = 0; m < 4; ++m)
#pragma unroll
        for (int n = 0; n < 2; ++n) acc[m][n] = (f32x4){0.f, 0.f, 0.f, 0.f};

    stage_ab(Abf, As, Bs, rowA, colB, 0, t);
    __syncthreads();

    for (int kc = 0; kc < 8; ++kc) {
        const int cur = kc & 1;
        if (kc < 7)
            stage_ab(Abf, As + (cur ^ 1) * ATILE, Bs + (cur ^ 1) * BTILE,
                     rowA, colB, (kc + 1) * 64, t);

        const char* AsB = (const char*)(As + cur * ATILE);
        const char* BsB = (const char*)(Bs + cur * BTILE);
#pragma unroll
        for (int kk = 0; kk < 2; ++kk) {
            s16x8 af[4], bfr[2];
#pragma unroll
            for (int m = 0; m < 4; ++m) {
                const int row = wr * 64 + m * 16 + lrow;
                af[m] = *(const s16x8*)(AsB + row * 128 + (((kk * 4 + lgrp) ^ (row & 7)) * 16));
            }
#pragma unroll
            for (int n = 0; n < 2; ++n) {
                const int row = wc * 32 + n * 16 + lrow;   // B tile row 0..63
                bfr[n] = *(const s16x8*)(BsB + row * 128 + (((kk * 4 + lgrp) ^ (row & 7)) * 16));
            }
#pragma unroll
            for (int m = 0; m < 4; ++m)
#pragma unroll
                for (int n = 0; n < 2; ++n)
                    acc[m][n] = __builtin_amdgcn_mfma_f32_16x16x32_bf16(af[m], bfr[n], acc[m][n], 0, 0, 0);
        }
        __syncthreads();
    }

    // C/D layout: col = lane&15, row = (lane>>4)*4 + j ; store MAPPED u16.
#pragma unroll
    for (int m = 0; m < 4; ++m) {
#pragma unroll
        for (int n = 0; n < 2; ++n) {
            const int col = colB + wc * 32 + n * 16 + lrow;
            const int row0 = rowA + wr * 64 + m * 16 + lgrp * 4;
#pragma unroll
            for (int j = 0; j < 4; ++j)
                C[(size_t)(row0 + j) * N + col] = mapbf(acc[m][n][j]);
        }
    }
    if (bi != bj) {
#pragma unroll
        for (int m = 0; m < 4; ++m) {
#pragma unroll
            for (int n = 0; n < 2; ++n) {
                const int col = colB + wc * 32 + n * 16 + lrow;
                const int row0 = rowA + wr * 64 + m * 16 + lgrp * 4;
                ushort4 pk;
                pk.x = mapbf(acc[m][n][0]);
                pk.y = mapbf(acc[m][n][1]);
                pk.z = mapbf(acc[m][n][2]);
                pk.w = mapbf(acc[m][n][3]);
                *(ushort4*)&C[(size_t)col * N + row0] = pk;
            }
        }
    }
}

// ---------------------------------------------------------------------------
// Kernel 3: wave-per-row top-5 / bottom-10 over pre-mapped u16 sim.
// TWO independent cascade chains (A/B over alternating 16B groups) for
// per-wave ILP on the dependent bubble chains; fold B into A, then wave
// merge. key = u16<<16 | idx (idx ^0xFFF for top -> jax stable ties).
// ---------------------------------------------------------------------------
__device__ __forceinline__ void ins_top(unsigned* tk, unsigned c) {
#pragma unroll
    for (int q = 0; q < KPOS - 1; ++q) {
        const unsigned x = umax_(tk[q], c);
        c = umin_(tk[q], c);
        tk[q] = x;
    }
    tk[KPOS - 1] = umax_(tk[KPOS - 1], c);
}
__device__ __forceinline__ void ins_bot(unsigned* bk, unsigned c) {
#pragma unroll
    for (int q = 0; q < KNEG - 1; ++q) {
        const unsigned x = umin_(bk[q], c);
        c = umax_(bk[q], c);
        bk[q] = x;
    }
    bk[KNEG - 1] = umin_(bk[KNEG - 1], c);   // r13 had umax here: lane kept only bot-9
}
__device__ __forceinline__ void scan8(const unsigned short* __restrict__ s,
                                      int lane, int e, unsigned* tk, unsigned* bk) {
    const int base = 8 * (lane + 64 * e);
    const u16x8 v8 = *(const u16x8*)&s[base];
#pragma unroll
    for (int j = 0; j < 8; ++j) {
        const unsigned kv = ((unsigned)v8[j]) << 16;   // pre-mapped, sortable
        const int idx = base + j;
        ins_top(tk, kv | (unsigned)(idx ^ 0xFFF));
        ins_bot(bk, kv | (unsigned)idx);
    }
}

__global__ __launch_bounds__(256) void topk_kernel(const unsigned short* __restrict__ sim,
                                                   int* __restrict__ pos_idx,
                                                   int* __restrict__ neg_idx) {
    const int w = threadIdx.x >> 6, l = threadIdx.x & 63;
    const int row = blockIdx.x * 4 + w;
    const unsigned short* s = sim + (size_t)row * N;

    unsigned tkA[KPOS], bkA[KNEG], tkB[KPOS], bkB[KNEG];
#pragma unroll
    for (int q = 0; q < KPOS; ++q) { tkA[q] = 0u; tkB[q] = 0u; }
#pragma unroll
    for (int q = 0; q < KNEG; ++q) { bkA[q] = 0xFFFFFFFFu; bkB[q] = 0xFFFFFFFFu; }

#pragma unroll
    for (int ee = 0; ee < 4; ++ee) {
        scan8(s, l, 2 * ee, tkA, bkA);       // chain A
        scan8(s, l, 2 * ee + 1, tkB, bkB);   // chain B (independent -> ILP)
    }
    // fold B into A
#pragma unroll
    for (int q = 0; q < KPOS; ++q) ins_top(tkA, tkB[q]);
#pragma unroll
    for (int q = 0; q < KNEG; ++q) ins_bot(bkA, bkB[q]);

    // ---- merge top-5 across the wave ----
#pragma unroll
    for (int it = 0; it < KPOS; ++it) {
        unsigned m = tkA[0];
#pragma unroll
        for (int off = 32; off > 0; off >>= 1) m = umax_(m, (unsigned)__shfl_xor((int)m, off));
        if (l == 0) pos_idx[row * KPOS + it] = (int)((m & 0xFFFu) ^ 0xFFFu);
        if (tkA[0] == m) {   // unique key -> exactly one lane pops
#pragma unroll
            for (int q = 0; q < KPOS - 1; ++q) tkA[q] = tkA[q + 1];
            tkA[KPOS - 1] = 0u;
        }
    }
    // ---- merge bottom-10 across the wave ----
#pragma unroll
    for (int it = 0; it < KNEG; ++it) {
        unsigned m = bkA[0];
#pragma unroll
        for (int off = 32; off > 0; off >>= 1) m = umin_(m, (unsigned)__shfl_xor((int)m, off));
        if (l == 0) neg_idx[row * KNEG + it] = (int)(m & 0xFFFu);
        if (bkA[0] == m) {
#pragma unroll
            for (int q = 0; q < KNEG - 1; ++q) bkA[q] = bkA[q + 1];
            bkA[KNEG - 1] = 0xFFFFFFFFu;
        }
    }
}

// ---------------------------------------------------------------------------
// Kernel 4: MFMA InfoNCE loss. One wave per anchor ia.
// A rows = 5 query rows (dup 0), B cols = 5 pos + 10 neg (+dup).
// All 32 16B gathers issued up-front, PINNED with sched_barrier(0) so the
// compiler cannot sink them into the MFMA chain (r13: VGPR=36 proved it had).
// 16-lane-group softmax; block partial -> partials[].
// ---------------------------------------------------------------------------
__global__ __launch_bounds__(256) void loss_kernel(const unsigned short* __restrict__ s_norm,
                                                   const int* __restrict__ pos_idx,
                                                   const int* __restrict__ neg_idx,
                                                   float* __restrict__ partials) {
    __shared__ float wsum[4];
    const int wave = threadIdx.x >> 6, lane = threadIdx.x & 63;
    const int ia = blockIdx.x * 4 + wave;
    const int cc = lane & 15;               // column selector
    const int g = lane >> 4;                // k-group

    const int qbase = ia * KPOS;
    const int rowA = (qbase + ((cc < KPOS) ? cc : 0)) & (N - 1);
    int rowB;
    if (cc < KPOS)      rowB = pos_idx[qbase + cc];
    else if (cc < 15)   rowB = neg_idx[ia * KNEG + (cc - KPOS)];
    else                rowB = pos_idx[qbase];

    const unsigned short* pA = s_norm + (size_t)rowA * D + g * 8;
    const unsigned short* pB = s_norm + (size_t)rowB * D + g * 8;

    s16x8 a[16], b[16];
#pragma unroll
    for (int kk = 0; kk < 16; ++kk) {
        a[kk] = *(const s16x8*)(pA + kk * 32);
        b[kk] = *(const s16x8*)(pB + kk * 32);
    }
    __builtin_amdgcn_sched_barrier(0);      // pin: all 32 loads issued first
    asm volatile("" ::: "memory");

    f32x4 acc = (f32x4){0.f, 0.f, 0.f, 0.f};
#pragma unroll
    for (int kk = 0; kk < 16; ++kk)
        acc = __builtin_amdgcn_mfma_f32_16x16x32_bf16(a[kk], b[kk], acc, 0, 0, 0);

    float lsum = 0.f;
#pragma unroll
    for (int j = 0; j < 4; ++j) {
        const int p = g * 4 + j;                 // output row (query p)
        const float logit = acc[j] * 10.f;
        const bool isneg = (cc >= KPOS) && (cc < 15);
        const bool ispos = (cc == p);
        float x = (ispos || isneg) ? logit : -__builtin_inff();
        float m = x;
#pragma unroll
        for (int off = 1; off < 16; off <<= 1) m = fmaxf(m, __shfl_xor(m, off));
        float e = (ispos || isneg) ? expf(logit - m) : 0.f;
        float sx = e;
#pragma unroll
        for (int off = 1; off < 16; off <<= 1) sx += __shfl_xor(sx, off);
        float l0 = ispos ? logit : 0.f;
#pragma unroll
        for (int off = 1; off < 16; off <<= 1) l0 += __shfl_xor(l0, off);
        if (p < KPOS && ispos) lsum += logf(sx) + m - l0;   // one lane per row
    }

#pragma unroll
    for (int off = 32; off > 0; off >>= 1) lsum += __shfl_xor(lsum, off);
    if (lane == 0) wsum[wave] = lsum;
    __syncthreads();
    if (threadIdx.x == 0)
        partials[blockIdx.x] = wsum[0] + wsum[1] + wsum[2] + wsum[3];
}

// ---------------------------------------------------------------------------
// Kernel 5: final deterministic reduce of 1024 block partials.
// ---------------------------------------------------------------------------
__global__ __launch_bounds__(256) void reduce_kernel(const float* __restrict__ partials,
                                                     float* __restrict__ out) {
    __shared__ float wsum[4];
    const int wave = threadIdx.x >> 6, lane = threadIdx.x & 63;
    float s = partials[threadIdx.x] + partials[threadIdx.x + 256] +
              partials[threadIdx.x + 512] + partials[threadIdx.x + 768];
#pragma unroll
    for (int off = 32; off > 0; off >>= 1) s += __shfl_xor(s, off);
    if (lane == 0) wsum[wave] = s;
    __syncthreads();
    if (threadIdx.x == 0)
        *out = (wsum[0] + wsum[1] + wsum[2] + wsum[3]) * (1.0f / (float)(N * KPOS));
}

// ---------------------------------------------------------------------------
extern "C" void kernel_launch(void* const* d_in, const int* in_sizes, int n_in,
                              void* d_out, int out_size, void* d_ws, size_t ws_size,
                              hipStream_t stream) {
    const float* anchor = (const float*)d_in[0];
    const float* sample = (const float*)d_in[1];
    float* out = (float*)d_out;

    char* ws = (char*)d_ws;
    unsigned short* Abf    = (unsigned short*)ws;                               // 4 MiB
    unsigned short* s_norm = (unsigned short*)(ws + (size_t)4 * 1024 * 1024);   // 4 MiB
    unsigned short* sim    = (unsigned short*)(ws + (size_t)8 * 1024 * 1024);   // 32 MiB
    int* pos_idx  = (int*)(ws + (size_t)40 * 1024 * 1024);                      // 80 KiB
    int* neg_idx  = (int*)(ws + (size_t)40 * 1024 * 1024 + 128 * 1024);         // 160 KiB
    float* partials = (float*)(ws + (size_t)41 * 1024 * 1024);                  // 4 KiB

    norm_kernel<<<2048, 256, 0, stream>>>(anchor, sample, Abf, s_norm);

    gemm_bf16<<<NJOB, 256, 0, stream>>>(Abf, sim);

    topk_kernel<<<N / 4, 256, 0, stream>>>(sim, pos_idx, neg_idx);

    loss_kernel<<<N / 4, 256, 0, stream>>>(s_norm, pos_idx, neg_idx, partials);

    reduce_kernel<<<1, 256, 0, stream>>>(partials, out);
}

// Round 15
// 66.528 us; speedup vs baseline: 1.2823x; 1.0674x over previous
//
#include <hip/hip_runtime.h>
#include <math.h>

#define N 4096
#define D 512
#define KPOS 5
#define KNEG 10
#define NB 32                      // 4096/128 block-rows
#define NPAIR (NB * (NB - 1) / 2)  // 496 strict upper pairs
#define NJOB 1024                  // 992 off-diag half-jobs + 32 diag half-jobs

typedef short s16x8 __attribute__((ext_vector_type(8)));
typedef unsigned short u16x8 __attribute__((ext_vector_type(8)));
typedef float f32x4 __attribute__((ext_vector_type(4)));

__device__ __forceinline__ unsigned short f2bf(float x) {
    unsigned u = __float_as_uint(x);
    unsigned r = (u + 0x7FFFu + ((u >> 16) & 1u)) >> 16;   // RNE
    return (unsigned short)r;
}
__device__ __forceinline__ float bf2f(unsigned short b) {
    return __uint_as_float(((unsigned)b) << 16);
}
// bf16 -> sortable u16 (ascending u16 order == ascending float order)
__device__ __forceinline__ unsigned short mapbf(float x) {
    const unsigned short h = f2bf(x);
    return h ^ ((h & 0x8000u) ? 0xFFFFu : 0x8000u);
}
__device__ __forceinline__ unsigned umax_(unsigned a, unsigned b) { return a > b ? a : b; }
__device__ __forceinline__ unsigned umin_(unsigned a, unsigned b) { return a < b ? a : b; }

// ---------------------------------------------------------------------------
// Kernel 1: normalize. anchor rows (eps 1e-8) -> bf16 A; sample rows
// (eps 1e-12) -> bf16 s_norm. float4 input loads (2/lane).
// ---------------------------------------------------------------------------
__global__ __launch_bounds__(256) void norm_kernel(const float* __restrict__ anchor,
                                                   const float* __restrict__ sample,
                                                   unsigned short* __restrict__ Abf,
                                                   unsigned short* __restrict__ s_norm) {
    const int wave = threadIdx.x >> 6, lane = threadIdx.x & 63;
    const int row = blockIdx.x * 4 + wave;
    const bool is_anchor = row < N;
    const float* in = is_anchor ? anchor + (size_t)row * D
                                : sample + (size_t)(row - N) * D;
    const float eps = is_anchor ? 1e-8f : 1e-12f;

    const float4 v0 = *(const float4*)&in[lane * 4];
    const float4 v1 = *(const float4*)&in[256 + lane * 4];
    float ss = v0.x * v0.x + v0.y * v0.y + v0.z * v0.z + v0.w * v0.w
             + v1.x * v1.x + v1.y * v1.y + v1.z * v1.z + v1.w * v1.w;
#pragma unroll
    for (int off = 32; off > 0; off >>= 1) ss += __shfl_xor(ss, off);
    const float inv = 1.0f / fmaxf(sqrtf(ss), eps);

    unsigned short* out = is_anchor ? Abf + (size_t)row * D
                                    : s_norm + (size_t)(row - N) * D;
    ushort4 o0, o1;
    o0.x = f2bf(v0.x * inv); o0.y = f2bf(v0.y * inv);
    o0.z = f2bf(v0.z * inv); o0.w = f2bf(v0.w * inv);
    o1.x = f2bf(v1.x * inv); o1.y = f2bf(v1.y * inv);
    o1.z = f2bf(v1.z * inv); o1.w = f2bf(v1.w * inv);
    *(ushort4*)&out[lane * 4] = o0;
    *(ushort4*)&out[256 + lane * 4] = o1;
}

// ---------------------------------------------------------------------------
// Kernel 2: sim = A@A^T, bf16 MFMA, K = 512. 1024 balanced half-jobs
// (128 rows x 64 cols). Output = SORTABLE-MAPPED u16. Off-diag jobs write
// normal + transposed mirror. T1 XCD chunk swizzle, T2 LDS XOR swizzle via
// pre-swizzled global source, dbuf prefetch-before-compute.
// ---------------------------------------------------------------------------
#define ATILE (128 * 64)
#define BTILE (64 * 64)

__device__ __forceinline__ void stage_ab(const unsigned short* __restrict__ A,
                                         unsigned short* As, unsigned short* Bs,
                                         int rowA, int colB, int kl, int t) {
#pragma unroll
    for (int i = 0; i < 4; ++i) {
        const int c = i * 256 + t;                 // 16B chunk id 0..1023
        const int r = c >> 3;                      // tile row 0..127
        const int ke = ((c & 7) ^ (r & 7)) * 8;    // swizzled k-element offset
        __builtin_amdgcn_global_load_lds(
            (const __attribute__((address_space(1))) void*)(A + (size_t)(rowA + r) * D + kl + ke),
            (__attribute__((address_space(3))) void*)(As + c * 8), 16, 0, 0);
    }
#pragma unroll
    for (int i = 0; i < 2; ++i) {
        const int c = i * 256 + t;                 // 0..511
        const int r = c >> 3;                      // B tile row 0..63
        const int ke = ((c & 7) ^ (r & 7)) * 8;
        __builtin_amdgcn_global_load_lds(
            (const __attribute__((address_space(1))) void*)(A + (size_t)(colB + r) * D + kl + ke),
            (__attribute__((address_space(3))) void*)(Bs + c * 8), 16, 0, 0);
    }
}

__global__ __launch_bounds__(256) void gemm_bf16(const unsigned short* __restrict__ Abf,
                                                 unsigned short* __restrict__ C) {
    // T1: XCD chunk swizzle (bijective, NJOB % 8 == 0).
    const int q = (blockIdx.x % 8) * (NJOB / 8) + blockIdx.x / 8;

    int bi, bj, h;
    if (q < 2 * NPAIR) {
        const int op = q >> 1;                 // strict pair index 0..495
        h = q & 1;
        bi = (int)(31.5f - sqrtf(31.5f * 31.5f - 2.f * (float)op));
        while (31 * bi - bi * (bi - 1) / 2 > op) --bi;
        while (31 * (bi + 1) - (bi + 1) * bi / 2 <= op) ++bi;
        bj = bi + 1 + (op - (31 * bi - bi * (bi - 1) / 2));
    } else {
        const int d = q - 2 * NPAIR;           // 0..31
        bi = bj = d >> 1;
        h = d & 1;
    }

    __shared__ __align__(16) unsigned short As[2 * ATILE];   // 2 x 16 KiB
    __shared__ __align__(16) unsigned short Bs[2 * BTILE];   // 2 x 8 KiB

    const int t = threadIdx.x;
    const int l = t & 63;
    const int w = t >> 6;
    const int wr = w >> 1, wc = w & 1;         // wave tile: 64 rows x 32 cols
    const int rowA = bi * 128;
    const int colB = bj * 128 + h * 64;
    const int lrow = l & 15, lgrp = l >> 4;

    f32x4 acc[4][2];
#pragma unroll
    for (int m = 0; m < 4; ++m)
#pragma unroll
        for (int n = 0; n < 2; ++n) acc[m][n] = (f32x4){0.f, 0.f, 0.f, 0.f};

    stage_ab(Abf, As, Bs, rowA, colB, 0, t);
    __syncthreads();

    for (int kc = 0; kc < 8; ++kc) {
        const int cur = kc & 1;
        if (kc < 7)
            stage_ab(Abf, As + (cur ^ 1) * ATILE, Bs + (cur ^ 1) * BTILE,
                     rowA, colB, (kc + 1) * 64, t);

        const char* AsB = (const char*)(As + cur * ATILE);
        const char* BsB = (const char*)(Bs + cur * BTILE);
#pragma unroll
        for (int kk = 0; kk < 2; ++kk) {
            s16x8 af[4], bfr[2];
#pragma unroll
            for (int m = 0; m < 4; ++m) {
                const int row = wr * 64 + m * 16 + lrow;
                af[m] = *(const s16x8*)(AsB + row * 128 + (((kk * 4 + lgrp) ^ (row & 7)) * 16));
            }
#pragma unroll
            for (int n = 0; n < 2; ++n) {
                const int row = wc * 32 + n * 16 + lrow;   // B tile row 0..63
                bfr[n] = *(const s16x8*)(BsB + row * 128 + (((kk * 4 + lgrp) ^ (row & 7)) * 16));
            }
#pragma unroll
            for (int m = 0; m < 4; ++m)
#pragma unroll
                for (int n = 0; n < 2; ++n)
                    acc[m][n] = __builtin_amdgcn_mfma_f32_16x16x32_bf16(af[m], bfr[n], acc[m][n], 0, 0, 0);
        }
        __syncthreads();
    }

    // C/D layout: col = lane&15, row = (lane>>4)*4 + j ; store MAPPED u16.
#pragma unroll
    for (int m = 0; m < 4; ++m) {
#pragma unroll
        for (int n = 0; n < 2; ++n) {
            const int col = colB + wc * 32 + n * 16 + lrow;
            const int row0 = rowA + wr * 64 + m * 16 + lgrp * 4;
#pragma unroll
            for (int j = 0; j < 4; ++j)
                C[(size_t)(row0 + j) * N + col] = mapbf(acc[m][n][j]);
        }
    }
    if (bi != bj) {
#pragma unroll
        for (int m = 0; m < 4; ++m) {
#pragma unroll
            for (int n = 0; n < 2; ++n) {
                const int col = colB + wc * 32 + n * 16 + lrow;
                const int row0 = rowA + wr * 64 + m * 16 + lgrp * 4;
                ushort4 pk;
                pk.x = mapbf(acc[m][n][0]);
                pk.y = mapbf(acc[m][n][1]);
                pk.z = mapbf(acc[m][n][2]);
                pk.w = mapbf(acc[m][n][3]);
                *(ushort4*)&C[(size_t)col * N + row0] = pk;
            }
        }
    }
}

// ---------------------------------------------------------------------------
// Kernel 3: FUSED topk + loss (r12 structure — no counter, no atomics).
// One wave per anchor row ia.
// Phase A: branchless top-5/bot-10 over pre-mapped u16 sim, TWO independent
// cascade chains (ILP), fold, wave merge; winner indices captured into rowB
// via predicated select (no global idx round-trip).
// Phase B: MFMA loss — A rows = 5 query rows, B cols = 5 pos + 10 neg;
// all 32 16B gathers issued then pinned (sched_barrier 0), 16 chained MFMAs,
// 16-lane-group softmax. Block partial -> partials[].
// ---------------------------------------------------------------------------
__device__ __forceinline__ void ins_top(unsigned* tk, unsigned c) {
#pragma unroll
    for (int q = 0; q < KPOS - 1; ++q) {
        const unsigned x = umax_(tk[q], c);
        c = umin_(tk[q], c);
        tk[q] = x;
    }
    tk[KPOS - 1] = umax_(tk[KPOS - 1], c);
}
__device__ __forceinline__ void ins_bot(unsigned* bk, unsigned c) {
#pragma unroll
    for (int q = 0; q < KNEG - 1; ++q) {
        const unsigned x = umin_(bk[q], c);
        c = umax_(bk[q], c);
        bk[q] = x;
    }
    bk[KNEG - 1] = umin_(bk[KNEG - 1], c);
}
__device__ __forceinline__ void scan8(const unsigned short* __restrict__ s,
                                      int lane, int e, unsigned* tk, unsigned* bk) {
    const int base = 8 * (lane + 64 * e);
    const u16x8 v8 = *(const u16x8*)&s[base];
#pragma unroll
    for (int j = 0; j < 8; ++j) {
        const unsigned kv = ((unsigned)v8[j]) << 16;   // pre-mapped, sortable
        const int idx = base + j;
        ins_top(tk, kv | (unsigned)(idx ^ 0xFFF));
        ins_bot(bk, kv | (unsigned)idx);
    }
}

__global__ __launch_bounds__(256) void fused_topk_loss(const unsigned short* __restrict__ sim,
                                                       const unsigned short* __restrict__ s_norm,
                                                       float* __restrict__ partials) {
    __shared__ float wsum[4];
    const int wave = threadIdx.x >> 6, lane = threadIdx.x & 63;
    const int ia = blockIdx.x * 4 + wave;
    const unsigned short* s = sim + (size_t)ia * N;
    const int cc = lane & 15;               // loss column selector
    const int g = lane >> 4;                // loss k-group

    unsigned tkA[KPOS], bkA[KNEG], tkB[KPOS], bkB[KNEG];
#pragma unroll
    for (int q = 0; q < KPOS; ++q) { tkA[q] = 0u; tkB[q] = 0u; }
#pragma unroll
    for (int q = 0; q < KNEG; ++q) { bkA[q] = 0xFFFFFFFFu; bkB[q] = 0xFFFFFFFFu; }

#pragma unroll
    for (int ee = 0; ee < 4; ++ee) {
        scan8(s, lane, 2 * ee, tkA, bkA);       // chain A
        scan8(s, lane, 2 * ee + 1, tkB, bkB);   // chain B (independent -> ILP)
    }
#pragma unroll
    for (int q = 0; q < KPOS; ++q) ins_top(tkA, tkB[q]);
#pragma unroll
    for (int q = 0; q < KNEG; ++q) ins_bot(bkA, bkB[q]);

    int rowB = 0;                            // (cc==15 dummy stays 0)
#pragma unroll
    for (int it = 0; it < KPOS; ++it) {
        unsigned m = tkA[0];
#pragma unroll
        for (int off = 32; off > 0; off >>= 1) m = umax_(m, (unsigned)__shfl_xor((int)m, off));
        if (cc == it) rowB = (int)((m & 0xFFFu) ^ 0xFFFu);
        if (tkA[0] == m) {   // unique key -> exactly one lane pops
#pragma unroll
            for (int q = 0; q < KPOS - 1; ++q) tkA[q] = tkA[q + 1];
            tkA[KPOS - 1] = 0u;
        }
    }
#pragma unroll
    for (int it = 0; it < KNEG; ++it) {
        unsigned m = bkA[0];
#pragma unroll
        for (int off = 32; off > 0; off >>= 1) m = umin_(m, (unsigned)__shfl_xor((int)m, off));
        if (cc == KPOS + it) rowB = (int)(m & 0xFFFu);
        if (bkA[0] == m) {
#pragma unroll
            for (int q = 0; q < KNEG - 1; ++q) bkA[q] = bkA[q + 1];
            bkA[KNEG - 1] = 0xFFFFFFFFu;
        }
    }

    // ---- loss: A rows = query rows (ia*5+p mod N), B cols = pos/neg ----
    const int rowA = (ia * KPOS + ((cc < KPOS) ? cc : 0)) & (N - 1);
    const unsigned short* pA = s_norm + (size_t)rowA * D + g * 8;
    const unsigned short* pB = s_norm + (size_t)rowB * D + g * 8;

    s16x8 a[16], b[16];
#pragma unroll
    for (int kk = 0; kk < 16; ++kk) {
        a[kk] = *(const s16x8*)(pA + kk * 32);
        b[kk] = *(const s16x8*)(pB + kk * 32);
    }
    __builtin_amdgcn_sched_barrier(0);      // pin: all 32 loads issued first
    asm volatile("" ::: "memory");

    f32x4 acc = (f32x4){0.f, 0.f, 0.f, 0.f};
#pragma unroll
    for (int kk = 0; kk < 16; ++kk)
        acc = __builtin_amdgcn_mfma_f32_16x16x32_bf16(a[kk], b[kk], acc, 0, 0, 0);

    float lsum = 0.f;
#pragma unroll
    for (int j = 0; j < 4; ++j) {
        const int p = g * 4 + j;                 // output row (query p)
        const float logit = acc[j] * 10.f;
        const bool isneg = (cc >= KPOS) && (cc < 15);
        const bool ispos = (cc == p);
        float x = (ispos || isneg) ? logit : -__builtin_inff();
        float m = x;
#pragma unroll
        for (int off = 1; off < 16; off <<= 1) m = fmaxf(m, __shfl_xor(m, off));
        float e = (ispos || isneg) ? expf(logit - m) : 0.f;
        float sx = e;
#pragma unroll
        for (int off = 1; off < 16; off <<= 1) sx += __shfl_xor(sx, off);
        float l0 = ispos ? logit : 0.f;
#pragma unroll
        for (int off = 1; off < 16; off <<= 1) l0 += __shfl_xor(l0, off);
        if (p < KPOS && ispos) lsum += logf(sx) + m - l0;   // one lane per row
    }

#pragma unroll
    for (int off = 32; off > 0; off >>= 1) lsum += __shfl_xor(lsum, off);
    if (lane == 0) wsum[wave] = lsum;
    __syncthreads();
    if (threadIdx.x == 0)
        partials[blockIdx.x] = wsum[0] + wsum[1] + wsum[2] + wsum[3];
}

// ---------------------------------------------------------------------------
// Kernel 4: final deterministic reduce of 1024 block partials.
// ---------------------------------------------------------------------------
__global__ __launch_bounds__(256) void reduce_kernel(const float* __restrict__ partials,
                                                     float* __restrict__ out) {
    __shared__ float wsum[4];
    const int wave = threadIdx.x >> 6, lane = threadIdx.x & 63;
    float s = partials[threadIdx.x] + partials[threadIdx.x + 256] +
              partials[threadIdx.x + 512] + partials[threadIdx.x + 768];
#pragma unroll
    for (int off = 32; off > 0; off >>= 1) s += __shfl_xor(s, off);
    if (lane == 0) wsum[wave] = s;
    __syncthreads();
    if (threadIdx.x == 0)
        *out = (wsum[0] + wsum[1] + wsum[2] + wsum[3]) * (1.0f / (float)(N * KPOS));
}

// ---------------------------------------------------------------------------
extern "C" void kernel_launch(void* const* d_in, const int* in_sizes, int n_in,
                              void* d_out, int out_size, void* d_ws, size_t ws_size,
                              hipStream_t stream) {
    const float* anchor = (const float*)d_in[0];
    const float* sample = (const float*)d_in[1];
    float* out = (float*)d_out;

    char* ws = (char*)d_ws;
    unsigned short* Abf    = (unsigned short*)ws;                               // 4 MiB
    unsigned short* s_norm = (unsigned short*)(ws + (size_t)4 * 1024 * 1024);   // 4 MiB
    unsigned short* sim    = (unsigned short*)(ws + (size_t)8 * 1024 * 1024);   // 32 MiB
    float* partials = (float*)(ws + (size_t)40 * 1024 * 1024);                  // 4 KiB

    norm_kernel<<<2048, 256, 0, stream>>>(anchor, sample, Abf, s_norm);

    gemm_bf16<<<NJOB, 256, 0, stream>>>(Abf, sim);

    fused_topk_loss<<<N / 4, 256, 0, stream>>>(sim, s_norm, partials);

    reduce_kernel<<<1, 256, 0, stream>>>(partials, out);
}

// Round 16
// 60.298 us; speedup vs baseline: 1.4147x; 1.1033x over previous
//
#include <hip/hip_runtime.h>
#include <math.h>

#define N 4096
#define D 512
#define KPOS 5
#define KNEG 10
#define NB 32                      // 4096/128 block-rows
#define NPAIR (NB * (NB - 1) / 2)  // 496 strict upper pairs
#define NJOB 1024                  // 992 off-diag half-jobs + 32 diag half-jobs

typedef short s16x8 __attribute__((ext_vector_type(8)));
typedef unsigned short u16x8 __attribute__((ext_vector_type(8)));
typedef float f32x4 __attribute__((ext_vector_type(4)));

__device__ __forceinline__ unsigned short f2bf(float x) {
    unsigned u = __float_as_uint(x);
    unsigned r = (u + 0x7FFFu + ((u >> 16) & 1u)) >> 16;   // RNE
    return (unsigned short)r;
}
__device__ __forceinline__ float bf2f(unsigned short b) {
    return __uint_as_float(((unsigned)b) << 16);
}
// bf16 -> sortable u16 (ascending u16 order == ascending float order)
__device__ __forceinline__ unsigned short mapbf(float x) {
    const unsigned short h = f2bf(x);
    return h ^ ((h & 0x8000u) ? 0xFFFFu : 0x8000u);
}
__device__ __forceinline__ unsigned umax_(unsigned a, unsigned b) { return a > b ? a : b; }
__device__ __forceinline__ unsigned umin_(unsigned a, unsigned b) { return a < b ? a : b; }

// ---------------------------------------------------------------------------
// Kernel 1: normalize. anchor rows (eps 1e-8) -> bf16 A; sample rows
// (eps 1e-12) -> bf16 s_norm. float4 input loads (2/lane).
// ---------------------------------------------------------------------------
__global__ __launch_bounds__(256) void norm_kernel(const float* __restrict__ anchor,
                                                   const float* __restrict__ sample,
                                                   unsigned short* __restrict__ Abf,
                                                   unsigned short* __restrict__ s_norm) {
    const int wave = threadIdx.x >> 6, lane = threadIdx.x & 63;
    const int row = blockIdx.x * 4 + wave;
    const bool is_anchor = row < N;
    const float* in = is_anchor ? anchor + (size_t)row * D
                                : sample + (size_t)(row - N) * D;
    const float eps = is_anchor ? 1e-8f : 1e-12f;

    const float4 v0 = *(const float4*)&in[lane * 4];
    const float4 v1 = *(const float4*)&in[256 + lane * 4];
    float ss = v0.x * v0.x + v0.y * v0.y + v0.z * v0.z + v0.w * v0.w
             + v1.x * v1.x + v1.y * v1.y + v1.z * v1.z + v1.w * v1.w;
#pragma unroll
    for (int off = 32; off > 0; off >>= 1) ss += __shfl_xor(ss, off);
    const float inv = 1.0f / fmaxf(sqrtf(ss), eps);

    unsigned short* out = is_anchor ? Abf + (size_t)row * D
                                    : s_norm + (size_t)(row - N) * D;
    ushort4 o0, o1;
    o0.x = f2bf(v0.x * inv); o0.y = f2bf(v0.y * inv);
    o0.z = f2bf(v0.z * inv); o0.w = f2bf(v0.w * inv);
    o1.x = f2bf(v1.x * inv); o1.y = f2bf(v1.y * inv);
    o1.z = f2bf(v1.z * inv); o1.w = f2bf(v1.w * inv);
    *(ushort4*)&out[lane * 4] = o0;
    *(ushort4*)&out[256 + lane * 4] = o1;
}

// ---------------------------------------------------------------------------
// Kernel 2: sim = A@A^T, bf16 MFMA, K = 512. 1024 balanced half-jobs
// (128 rows x 64 cols). Output = SORTABLE-MAPPED u16. Off-diag jobs write
// normal + transposed mirror. T1 XCD chunk swizzle, T2 LDS XOR swizzle via
// pre-swizzled global source, dbuf prefetch-before-compute.
// ---------------------------------------------------------------------------
#define ATILE (128 * 64)
#define BTILE (64 * 64)

__device__ __forceinline__ void stage_ab(const unsigned short* __restrict__ A,
                                         unsigned short* As, unsigned short* Bs,
                                         int rowA, int colB, int kl, int t) {
#pragma unroll
    for (int i = 0; i < 4; ++i) {
        const int c = i * 256 + t;                 // 16B chunk id 0..1023
        const int r = c >> 3;                      // tile row 0..127
        const int ke = ((c & 7) ^ (r & 7)) * 8;    // swizzled k-element offset
        __builtin_amdgcn_global_load_lds(
            (const __attribute__((address_space(1))) void*)(A + (size_t)(rowA + r) * D + kl + ke),
            (__attribute__((address_space(3))) void*)(As + c * 8), 16, 0, 0);
    }
#pragma unroll
    for (int i = 0; i < 2; ++i) {
        const int c = i * 256 + t;                 // 0..511
        const int r = c >> 3;                      // B tile row 0..63
        const int ke = ((c & 7) ^ (r & 7)) * 8;
        __builtin_amdgcn_global_load_lds(
            (const __attribute__((address_space(1))) void*)(A + (size_t)(colB + r) * D + kl + ke),
            (__attribute__((address_space(3))) void*)(Bs + c * 8), 16, 0, 0);
    }
}

__global__ __launch_bounds__(256) void gemm_bf16(const unsigned short* __restrict__ Abf,
                                                 unsigned short* __restrict__ C) {
    // T1: XCD chunk swizzle (bijective, NJOB % 8 == 0).
    const int q = (blockIdx.x % 8) * (NJOB / 8) + blockIdx.x / 8;

    int bi, bj, h;
    if (q < 2 * NPAIR) {
        const int op = q >> 1;                 // strict pair index 0..495
        h = q & 1;
        bi = (int)(31.5f - sqrtf(31.5f * 31.5f - 2.f * (float)op));
        while (31 * bi - bi * (bi - 1) / 2 > op) --bi;
        while (31 * (bi + 1) - (bi + 1) * bi / 2 <= op) ++bi;
        bj = bi + 1 + (op - (31 * bi - bi * (bi - 1) / 2));
    } else {
        const int d = q - 2 * NPAIR;           // 0..31
        bi = bj = d >> 1;
        h = d & 1;
    }

    __shared__ __align__(16) unsigned short As[2 * ATILE];   // 2 x 16 KiB
    __shared__ __align__(16) unsigned short Bs[2 * BTILE];   // 2 x 8 KiB

    const int t = threadIdx.x;
    const int l = t & 63;
    const int w = t >> 6;
    const int wr = w >> 1, wc = w & 1;         // wave tile: 64 rows x 32 cols
    const int rowA = bi * 128;
    const int colB = bj * 128 + h * 64;
    const int lrow = l & 15, lgrp = l >> 4;

    f32x4 acc[4][2];
#pragma unroll
    for (int m = 0; m < 4; ++m)
#pragma unroll
        for (int n = 0; n < 2; ++n) acc[m][n] = (f32x4){0.f, 0.f, 0.f, 0.f};

    stage_ab(Abf, As, Bs, rowA, colB, 0, t);
    __syncthreads();

    for (int kc = 0; kc < 8; ++kc) {
        const int cur = kc & 1;
        if (kc < 7)
            stage_ab(Abf, As + (cur ^ 1) * ATILE, Bs + (cur ^ 1) * BTILE,
                     rowA, colB, (kc + 1) * 64, t);

        const char* AsB = (const char*)(As + cur * ATILE);
        const char* BsB = (const char*)(Bs + cur * BTILE);
#pragma unroll
        for (int kk = 0; kk < 2; ++kk) {
            s16x8 af[4], bfr[2];
#pragma unroll
            for (int m = 0; m < 4; ++m) {
                const int row = wr * 64 + m * 16 + lrow;
                af[m] = *(const s16x8*)(AsB + row * 128 + (((kk * 4 + lgrp) ^ (row & 7)) * 16));
            }
#pragma unroll
            for (int n = 0; n < 2; ++n) {
                const int row = wc * 32 + n * 16 + lrow;   // B tile row 0..63
                bfr[n] = *(const s16x8*)(BsB + row * 128 + (((kk * 4 + lgrp) ^ (row & 7)) * 16));
            }
#pragma unroll
            for (int m = 0; m < 4; ++m)
#pragma unroll
                for (int n = 0; n < 2; ++n)
                    acc[m][n] = __builtin_amdgcn_mfma_f32_16x16x32_bf16(af[m], bfr[n], acc[m][n], 0, 0, 0);
        }
        __syncthreads();
    }

    // C/D layout: col = lane&15, row = (lane>>4)*4 + j ; store MAPPED u16.
#pragma unroll
    for (int m = 0; m < 4; ++m) {
#pragma unroll
        for (int n = 0; n < 2; ++n) {
            const int col = colB + wc * 32 + n * 16 + lrow;
            const int row0 = rowA + wr * 64 + m * 16 + lgrp * 4;
#pragma unroll
            for (int j = 0; j < 4; ++j)
                C[(size_t)(row0 + j) * N + col] = mapbf(acc[m][n][j]);
        }
    }
    if (bi != bj) {
#pragma unroll
        for (int m = 0; m < 4; ++m) {
#pragma unroll
            for (int n = 0; n < 2; ++n) {
                const int col = colB + wc * 32 + n * 16 + lrow;
                const int row0 = rowA + wr * 64 + m * 16 + lgrp * 4;
                ushort4 pk;
                pk.x = mapbf(acc[m][n][0]);
                pk.y = mapbf(acc[m][n][1]);
                pk.z = mapbf(acc[m][n][2]);
                pk.w = mapbf(acc[m][n][3]);
                *(ushort4*)&C[(size_t)col * N + row0] = pk;
            }
        }
    }
}

// ---------------------------------------------------------------------------
// Kernel 3: FUSED topk + loss. One wave per anchor row ia.
// Phase A: PRELOAD the entire 8 KB row into 32 VGPRs (8 x u16x8, all loads
// outstanding simultaneously — r15 was latency-bound with 1-2 in flight),
// pin with sched_barrier, then branchless dual-chain cascade on registers.
// Phase B: MFMA loss — A rows = 5 query rows, B cols = 5 pos + 10 neg;
// 32 pinned gathers, 16 chained MFMAs, 16-lane-group softmax.
// ---------------------------------------------------------------------------
__device__ __forceinline__ void ins_top(unsigned* tk, unsigned c) {
#pragma unroll
    for (int q = 0; q < KPOS - 1; ++q) {
        const unsigned x = umax_(tk[q], c);
        c = umin_(tk[q], c);
        tk[q] = x;
    }
    tk[KPOS - 1] = umax_(tk[KPOS - 1], c);
}
__device__ __forceinline__ void ins_bot(unsigned* bk, unsigned c) {
#pragma unroll
    for (int q = 0; q < KNEG - 1; ++q) {
        const unsigned x = umin_(bk[q], c);
        c = umax_(bk[q], c);
        bk[q] = x;
    }
    bk[KNEG - 1] = umin_(bk[KNEG - 1], c);
}
__device__ __forceinline__ void scan_reg(const u16x8 v8, int base,
                                         unsigned* tk, unsigned* bk) {
#pragma unroll
    for (int j = 0; j < 8; ++j) {
        const unsigned kv = ((unsigned)v8[j]) << 16;   // pre-mapped, sortable
        const int idx = base + j;
        ins_top(tk, kv | (unsigned)(idx ^ 0xFFF));
        ins_bot(bk, kv | (unsigned)idx);
    }
}

__global__ __launch_bounds__(256) void fused_topk_loss(const unsigned short* __restrict__ sim,
                                                       const unsigned short* __restrict__ s_norm,
                                                       float* __restrict__ partials) {
    __shared__ float wsum[4];
    const int wave = threadIdx.x >> 6, lane = threadIdx.x & 63;
    const int ia = blockIdx.x * 4 + wave;
    const unsigned short* s = sim + (size_t)ia * N;
    const int cc = lane & 15;               // loss column selector
    const int g = lane >> 4;                // loss k-group

    // ---- preload the whole row: 8 independent 16B loads, all in flight ----
    u16x8 v0 = *(const u16x8*)&s[8 * lane];
    u16x8 v1 = *(const u16x8*)&s[8 * (lane + 64)];
    u16x8 v2 = *(const u16x8*)&s[8 * (lane + 128)];
    u16x8 v3 = *(const u16x8*)&s[8 * (lane + 192)];
    u16x8 v4 = *(const u16x8*)&s[8 * (lane + 256)];
    u16x8 v5 = *(const u16x8*)&s[8 * (lane + 320)];
    u16x8 v6 = *(const u16x8*)&s[8 * (lane + 384)];
    u16x8 v7 = *(const u16x8*)&s[8 * (lane + 448)];
    __builtin_amdgcn_sched_barrier(0);      // pin: all 8 loads issued first
    asm volatile("" ::: "memory");

    unsigned tkA[KPOS], bkA[KNEG], tkB[KPOS], bkB[KNEG];
#pragma unroll
    for (int q = 0; q < KPOS; ++q) { tkA[q] = 0u; tkB[q] = 0u; }
#pragma unroll
    for (int q = 0; q < KNEG; ++q) { bkA[q] = 0xFFFFFFFFu; bkB[q] = 0xFFFFFFFFu; }

    scan_reg(v0, 8 * lane,         tkA, bkA);   // chain A
    scan_reg(v1, 8 * (lane + 64),  tkB, bkB);   // chain B (independent -> ILP)
    scan_reg(v2, 8 * (lane + 128), tkA, bkA);
    scan_reg(v3, 8 * (lane + 192), tkB, bkB);
    scan_reg(v4, 8 * (lane + 256), tkA, bkA);
    scan_reg(v5, 8 * (lane + 320), tkB, bkB);
    scan_reg(v6, 8 * (lane + 384), tkA, bkA);
    scan_reg(v7, 8 * (lane + 448), tkB, bkB);

#pragma unroll
    for (int q = 0; q < KPOS; ++q) ins_top(tkA, tkB[q]);
#pragma unroll
    for (int q = 0; q < KNEG; ++q) ins_bot(bkA, bkB[q]);

    int rowB = 0;                            // (cc==15 dummy stays 0)
#pragma unroll
    for (int it = 0; it < KPOS; ++it) {
        unsigned m = tkA[0];
#pragma unroll
        for (int off = 32; off > 0; off >>= 1) m = umax_(m, (unsigned)__shfl_xor((int)m, off));
        if (cc == it) rowB = (int)((m & 0xFFFu) ^ 0xFFFu);
        if (tkA[0] == m) {   // unique key -> exactly one lane pops
#pragma unroll
            for (int q = 0; q < KPOS - 1; ++q) tkA[q] = tkA[q + 1];
            tkA[KPOS - 1] = 0u;
        }
    }
#pragma unroll
    for (int it = 0; it < KNEG; ++it) {
        unsigned m = bkA[0];
#pragma unroll
        for (int off = 32; off > 0; off >>= 1) m = umin_(m, (unsigned)__shfl_xor((int)m, off));
        if (cc == KPOS + it) rowB = (int)(m & 0xFFFu);
        if (bkA[0] == m) {
#pragma unroll
            for (int q = 0; q < KNEG - 1; ++q) bkA[q] = bkA[q + 1];
            bkA[KNEG - 1] = 0xFFFFFFFFu;
        }
    }

    // ---- loss: A rows = query rows (ia*5+p mod N), B cols = pos/neg ----
    const int rowA = (ia * KPOS + ((cc < KPOS) ? cc : 0)) & (N - 1);
    const unsigned short* pA = s_norm + (size_t)rowA * D + g * 8;
    const unsigned short* pB = s_norm + (size_t)rowB * D + g * 8;

    s16x8 a[16], b[16];
#pragma unroll
    for (int kk = 0; kk < 16; ++kk) {
        a[kk] = *(const s16x8*)(pA + kk * 32);
        b[kk] = *(const s16x8*)(pB + kk * 32);
    }
    __builtin_amdgcn_sched_barrier(0);      // pin: all 32 loads issued first
    asm volatile("" ::: "memory");

    f32x4 acc = (f32x4){0.f, 0.f, 0.f, 0.f};
#pragma unroll
    for (int kk = 0; kk < 16; ++kk)
        acc = __builtin_amdgcn_mfma_f32_16x16x32_bf16(a[kk], b[kk], acc, 0, 0, 0);

    float lsum = 0.f;
#pragma unroll
    for (int j = 0; j < 4; ++j) {
        const int p = g * 4 + j;                 // output row (query p)
        const float logit = acc[j] * 10.f;
        const bool isneg = (cc >= KPOS) && (cc < 15);
        const bool ispos = (cc == p);
        float x = (ispos || isneg) ? logit : -__builtin_inff();
        float m = x;
#pragma unroll
        for (int off = 1; off < 16; off <<= 1) m = fmaxf(m, __shfl_xor(m, off));
        float e = (ispos || isneg) ? expf(logit - m) : 0.f;
        float sx = e;
#pragma unroll
        for (int off = 1; off < 16; off <<= 1) sx += __shfl_xor(sx, off);
        float l0 = ispos ? logit : 0.f;
#pragma unroll
        for (int off = 1; off < 16; off <<= 1) l0 += __shfl_xor(l0, off);
        if (p < KPOS && ispos) lsum += logf(sx) + m - l0;   // one lane per row
    }

#pragma unroll
    for (int off = 32; off > 0; off >>= 1) lsum += __shfl_xor(lsum, off);
    if (lane == 0) wsum[wave] = lsum;
    __syncthreads();
    if (threadIdx.x == 0)
        partials[blockIdx.x] = wsum[0] + wsum[1] + wsum[2] + wsum[3];
}

// ---------------------------------------------------------------------------
// Kernel 4: final deterministic reduce of 1024 block partials.
// ---------------------------------------------------------------------------
__global__ __launch_bounds__(256) void reduce_kernel(const float* __restrict__ partials,
                                                     float* __restrict__ out) {
    __shared__ float wsum[4];
    const int wave = threadIdx.x >> 6, lane = threadIdx.x & 63;
    float s = partials[threadIdx.x] + partials[threadIdx.x + 256] +
              partials[threadIdx.x + 512] + partials[threadIdx.x + 768];
#pragma unroll
    for (int off = 32; off > 0; off >>= 1) s += __shfl_xor(s, off);
    if (lane == 0) wsum[wave] = s;
    __syncthreads();
    if (threadIdx.x == 0)
        *out = (wsum[0] + wsum[1] + wsum[2] + wsum[3]) * (1.0f / (float)(N * KPOS));
}

// ---------------------------------------------------------------------------
extern "C" void kernel_launch(void* const* d_in, const int* in_sizes, int n_in,
                              void* d_out, int out_size, void* d_ws, size_t ws_size,
                              hipStream_t stream) {
    const float* anchor = (const float*)d_in[0];
    const float* sample = (const float*)d_in[1];
    float* out = (float*)d_out;

    char* ws = (char*)d_ws;
    unsigned short* Abf    = (unsigned short*)ws;                               // 4 MiB
    unsigned short* s_norm = (unsigned short*)(ws + (size_t)4 * 1024 * 1024);   // 4 MiB
    unsigned short* sim    = (unsigned short*)(ws + (size_t)8 * 1024 * 1024);   // 32 MiB
    float* partials = (float*)(ws + (size_t)40 * 1024 * 1024);                  // 4 KiB

    norm_kernel<<<2048, 256, 0, stream>>>(anchor, sample, Abf, s_norm);

    gemm_bf16<<<NJOB, 256, 0, stream>>>(Abf, sim);

    fused_topk_loss<<<N / 4, 256, 0, stream>>>(sim, s_norm, partials);

    reduce_kernel<<<1, 256, 0, stream>>>(partials, out);
}